// Round 1
// baseline (6185.730 us; speedup 1.0000x reference)
//
#include <hip/hip_runtime.h>
#include <hip/hip_bf16.h>
#include <math.h>

#define N_NODES 50000
#define EDGES   800000
#define META    4
#define IN_DIM  512
#define NHID    128
#define NCLS    2

// ---------------- GEMM: pre1 = x @ W1  [50000,512]x[512,128] fp32 ----------------
__global__ __launch_bounds__(256) void gemm_xw1(const float* __restrict__ A,
                                                const float* __restrict__ B,
                                                float* __restrict__ C) {
  const int BM = 64, BK = 32;
  __shared__ float As[64][33];
  __shared__ float Bs[32][128];
  int tid = threadIdx.x;
  int block_row = blockIdx.x * BM;
  int tm = tid >> 5;        // 0..7 -> rows tm*8..tm*8+7
  int tn = tid & 31;        // 0..31 -> cols tn*4..tn*4+3
  float acc[8][4] = {};

  for (int k0 = 0; k0 < IN_DIM; k0 += BK) {
    // load A tile 64x32 (512 float4, 2 per thread)
#pragma unroll
    for (int t = 0; t < 2; ++t) {
      int idx = t * 256 + tid;          // 0..511
      int row = idx >> 3, c4 = idx & 7;
      int grow = block_row + row;
      float4 v = make_float4(0.f, 0.f, 0.f, 0.f);
      if (grow < N_NODES)
        v = *reinterpret_cast<const float4*>(&A[(size_t)grow * IN_DIM + k0 + c4 * 4]);
      As[row][c4 * 4 + 0] = v.x; As[row][c4 * 4 + 1] = v.y;
      As[row][c4 * 4 + 2] = v.z; As[row][c4 * 4 + 3] = v.w;
    }
    // load B tile 32x128 (1024 float4, 4 per thread)
#pragma unroll
    for (int t = 0; t < 4; ++t) {
      int idx = t * 256 + tid;          // 0..1023
      int row = idx >> 5, c4 = idx & 31;
      float4 v = *reinterpret_cast<const float4*>(&B[(size_t)(k0 + row) * NHID + c4 * 4]);
      *reinterpret_cast<float4*>(&Bs[row][c4 * 4]) = v;
    }
    __syncthreads();
#pragma unroll
    for (int kk = 0; kk < BK; ++kk) {
      float a[8];
#pragma unroll
      for (int r = 0; r < 8; ++r) a[r] = As[tm * 8 + r][kk];
      float4 bv = *reinterpret_cast<const float4*>(&Bs[kk][tn * 4]);
      float b[4] = {bv.x, bv.y, bv.z, bv.w};
#pragma unroll
      for (int r = 0; r < 8; ++r)
#pragma unroll
        for (int j = 0; j < 4; ++j)
          acc[r][j] = fmaf(a[r], b[j], acc[r][j]);
    }
    __syncthreads();
  }
#pragma unroll
  for (int r = 0; r < 8; ++r) {
    int grow = block_row + tm * 8 + r;
    if (grow < N_NODES)
      *reinterpret_cast<float4*>(&C[(size_t)grow * NHID + tn * 4]) =
          make_float4(acc[r][0], acc[r][1], acc[r][2], acc[r][3]);
  }
}

// ---------------- SpMM layer 1: out[r,:128] += v * dense[c,:128] ----------------
__global__ __launch_bounds__(256) void spmm1_kernel(const int* __restrict__ rows,
                                                    const int* __restrict__ cols,
                                                    const float* __restrict__ vals,
                                                    const float* __restrict__ dense,
                                                    float* __restrict__ out, int nedges) {
  int gt = blockIdx.x * 256 + threadIdx.x;
  int e = gt >> 5;
  if (e >= nedges) return;
  int h4 = (gt & 31) * 4;
  int r = rows[e], c = cols[e];
  float v = vals[e];
  float4 d = *reinterpret_cast<const float4*>(&dense[(size_t)c * NHID + h4]);
  float* o = &out[(size_t)r * NHID + h4];
  atomicAdd(o + 0, v * d.x);
  atomicAdd(o + 1, v * d.y);
  atomicAdd(o + 2, v * d.z);
  atomicAdd(o + 3, v * d.w);
}

// ---------------- BN stats: per-channel sum and sumsq over nodes ----------------
__global__ __launch_bounds__(256) void bn_stats_kernel(const float* __restrict__ h1,
                                                       float* __restrict__ stats) {
  __shared__ float lds[256];
  int h = threadIdx.x & 127;
  int sub = threadIdx.x >> 7;
  float s = 0.f, ss = 0.f;
  int stride = gridDim.x * 2;
  for (int n = blockIdx.x * 2 + sub; n < N_NODES; n += stride) {
    float v = h1[(size_t)n * NHID + h];
    s += v;
    ss = fmaf(v, v, ss);
  }
  lds[threadIdx.x] = s;
  __syncthreads();
  if (sub == 0) s += lds[128 + h];
  __syncthreads();
  lds[threadIdx.x] = ss;
  __syncthreads();
  if (sub == 0) {
    ss += lds[128 + h];
    atomicAdd(&stats[h], s);
    atomicAdd(&stats[128 + h], ss);
  }
}

// ------------- BN apply + relu + @W2 : pre2[n,c] = sum_h relu(bn(h1)) * W2[h,c] -------------
__global__ __launch_bounds__(256) void bn_apply_kernel(const float* __restrict__ h1,
                                                       const float* __restrict__ stats,
                                                       const float* __restrict__ W2,
                                                       float* __restrict__ pre2) {
  int lane = threadIdx.x & 63;
  int wv = threadIdx.x >> 6;
  int n = blockIdx.x * 4 + wv;
  if (n >= N_NODES) return;
  const float inv_n = 1.0f / (float)N_NODES;
  float c0 = 0.f, c1 = 0.f;
#pragma unroll
  for (int t = 0; t < 2; ++t) {
    int h = lane + t * 64;
    float mean = stats[h] * inv_n;
    float var = stats[128 + h] * inv_n - mean * mean;
    float rs = rsqrtf(var + 1e-3f);
    float x = h1[(size_t)n * NHID + h];
    float y = (x - mean) * rs;
    y = y > 0.f ? y : 0.f;
    c0 = fmaf(y, W2[h * 2 + 0], c0);
    c1 = fmaf(y, W2[h * 2 + 1], c1);
  }
  for (int off = 32; off; off >>= 1) {
    c0 += __shfl_down(c0, off);
    c1 += __shfl_down(c1, off);
  }
  if (lane == 0) {
    pre2[(size_t)n * 2 + 0] = c0;
    pre2[(size_t)n * 2 + 1] = c1;
  }
}

// ---------------- SpMM layer 2 (2 channels), all metas ----------------
__global__ __launch_bounds__(256) void spmm2_kernel(const int* __restrict__ rows,
                                                    const int* __restrict__ cols,
                                                    const float* __restrict__ vals,
                                                    const float* __restrict__ pre2,
                                                    float* __restrict__ h2) {
  int gt = blockIdx.x * 256 + threadIdx.x;
  if (gt >= META * EDGES) return;
  int m = gt / EDGES;
  int e = gt - m * EDGES;
  size_t base = (size_t)m * EDGES + e;
  int r = rows[base], c = cols[base];
  float v = vals[base];
  float2 d = *reinterpret_cast<const float2*>(&pre2[((size_t)m * N_NODES + c) * 2]);
  float* o = &h2[((size_t)m * N_NODES + r) * 2];
  atomicAdd(o + 0, v * d.x);
  atomicAdd(o + 1, v * d.y);
}

// ---------------- attention dot: vacc[m,j] = sum_i h2[m,i]*w_omega[i,j] ----------------
__global__ __launch_bounds__(256) void att_dot_kernel(const float* __restrict__ h2,
                                                      const float* __restrict__ w_omega,
                                                      float* __restrict__ vacc) {
  float acc[16] = {};
  int stride = gridDim.x * blockDim.x;
  for (int i = blockIdx.x * blockDim.x + threadIdx.x; i < N_NODES * NCLS; i += stride) {
    float4 w = *reinterpret_cast<const float4*>(&w_omega[(size_t)i * 4]);
#pragma unroll
    for (int m = 0; m < 4; ++m) {
      float f = h2[(size_t)m * (N_NODES * NCLS) + i];
      acc[m * 4 + 0] = fmaf(f, w.x, acc[m * 4 + 0]);
      acc[m * 4 + 1] = fmaf(f, w.y, acc[m * 4 + 1]);
      acc[m * 4 + 2] = fmaf(f, w.z, acc[m * 4 + 2]);
      acc[m * 4 + 3] = fmaf(f, w.w, acc[m * 4 + 3]);
    }
  }
#pragma unroll
  for (int q = 0; q < 16; ++q) {
    float v = acc[q];
    for (int off = 32; off; off >>= 1) v += __shfl_down(v, off);
    if ((threadIdx.x & 63) == 0) atomicAdd(&vacc[q], v);
  }
}

// ---------------- attention finalize: alphas = softmax(tanh(vacc+b) @ u) ----------------
__global__ void att_final_kernel(const float* __restrict__ vacc,
                                 const float* __restrict__ b_omega,
                                 const float* __restrict__ u_omega,
                                 float* __restrict__ alphas) {
  if (threadIdx.x == 0 && blockIdx.x == 0) {
    float s[4];
    for (int m = 0; m < 4; ++m) {
      float sm = 0.f;
      for (int j = 0; j < 4; ++j)
        sm += tanhf(vacc[m * 4 + j] + b_omega[j]) * u_omega[j];
      s[m] = sm;
    }
    float mx = fmaxf(fmaxf(s[0], s[1]), fmaxf(s[2], s[3]));
    float ex[4], den = 0.f;
    for (int m = 0; m < 4; ++m) { ex[m] = expf(s[m] - mx); den += ex[m]; }
    for (int m = 0; m < 4; ++m) alphas[m] = ex[m] / den;
  }
}

// ---------------- sum of squares (for L2 reg) ----------------
__global__ __launch_bounds__(256) void sumsq_kernel(const float* __restrict__ p, int n,
                                                    float* __restrict__ out) {
  float s = 0.f;
  int stride = gridDim.x * blockDim.x;
  for (int i = blockIdx.x * blockDim.x + threadIdx.x; i < n; i += stride) {
    float v = p[i];
    s = fmaf(v, v, s);
  }
  for (int off = 32; off; off >>= 1) s += __shfl_down(s, off);
  if ((threadIdx.x & 63) == 0) atomicAdd(out, s);
}

// ---------------- per-node CE / acc / mask sums ----------------
__global__ __launch_bounds__(256) void loss_kernel(const float* __restrict__ h2,
                                                   const float* __restrict__ alphas,
                                                   const float* __restrict__ label,
                                                   const float* __restrict__ mask,
                                                   float* __restrict__ scal) {
  int n = blockIdx.x * blockDim.x + threadIdx.x;
  float msum = 0.f, cesum = 0.f, accsum = 0.f;
  if (n < N_NODES) {
    float a0 = alphas[0], a1 = alphas[1], a2 = alphas[2], a3 = alphas[3];
    const int S = N_NODES * NCLS;
    float l0 = a0 * h2[n * 2] + a1 * h2[S + n * 2] + a2 * h2[2 * S + n * 2] + a3 * h2[3 * S + n * 2];
    float l1 = a0 * h2[n * 2 + 1] + a1 * h2[S + n * 2 + 1] + a2 * h2[2 * S + n * 2 + 1] + a3 * h2[3 * S + n * 2 + 1];
    float mx = fmaxf(l0, l1);
    float lse = mx + logf(expf(l0 - mx) + expf(l1 - mx));
    float lb0 = label[n * 2], lb1 = label[n * 2 + 1];
    float ce = -(lb0 * (l0 - lse) + lb1 * (l1 - lse));
    int pred = (l1 > l0) ? 1 : 0;
    int larg = (lb1 > lb0) ? 1 : 0;
    float corr = (pred == larg) ? 1.f : 0.f;
    float mk = mask[n];
    msum = mk;
    cesum = ce * mk;
    accsum = corr * mk;
  }
  for (int off = 32; off; off >>= 1) {
    msum += __shfl_down(msum, off);
    cesum += __shfl_down(cesum, off);
    accsum += __shfl_down(accsum, off);
  }
  if ((threadIdx.x & 63) == 0) {
    atomicAdd(&scal[0], msum);
    atomicAdd(&scal[1], cesum);
    atomicAdd(&scal[2], accsum);
  }
}

__global__ void final_kernel(const float* __restrict__ scal, float* __restrict__ out) {
  if (threadIdx.x == 0 && blockIdx.x == 0) {
    out[0] = 5e-4f * 0.5f * scal[3] + scal[1] / scal[0];
    out[1] = scal[2] / scal[0];
  }
}

extern "C" void kernel_launch(void* const* d_in, const int* in_sizes, int n_in,
                              void* d_out, int out_size, void* d_ws, size_t ws_size,
                              hipStream_t stream) {
  const float* x       = (const float*)d_in[0];
  const float* W1      = (const float*)d_in[1];
  const float* W2      = (const float*)d_in[2];
  const float* w_omega = (const float*)d_in[3];
  const float* b_omega = (const float*)d_in[4];
  const float* u_omega = (const float*)d_in[5];
  const int*   sup_rows = (const int*)d_in[6];
  const int*   sup_cols = (const int*)d_in[7];
  const float* sup_vals = (const float*)d_in[8];
  const float* label   = (const float*)d_in[9];
  const float* mask    = (const float*)d_in[10];
  float* out = (float*)d_out;

  float* ws   = (float*)d_ws;
  float* pre1 = ws;                          // 6,400,000 floats
  float* h1m  = ws + 6400000;                // 6,400,000 floats (reused per meta)
  float* pre2 = ws + 12800000;               // 400,000 floats  [META][N][2]
  float* h2   = ws + 13200000;               // 400,000 floats  [META][N][2]
  float* stats  = ws + 13600000;             // 256
  float* vacc   = ws + 13600256;             // 16
  float* alphas = ws + 13600272;             // 4
  float* scal   = ws + 13600276;             // 8  [mask_sum, ce_sum, acc_sum, l2raw]

  // pre1 = x @ W1
  gemm_xw1<<<dim3((N_NODES + 63) / 64), dim3(256), 0, stream>>>(x, W1, pre1);

  hipMemsetAsync(scal, 0, 8 * sizeof(float), stream);
  hipMemsetAsync(vacc, 0, 16 * sizeof(float), stream);
  hipMemsetAsync(h2, 0, 400000 * sizeof(float), stream);

  for (int m = 0; m < META; ++m) {
    hipMemsetAsync(h1m, 0, 6400000 * sizeof(float), stream);
    hipMemsetAsync(stats, 0, 256 * sizeof(float), stream);
    spmm1_kernel<<<dim3(100000), dim3(256), 0, stream>>>(
        sup_rows + (size_t)m * EDGES, sup_cols + (size_t)m * EDGES,
        sup_vals + (size_t)m * EDGES, pre1, h1m, EDGES);
    bn_stats_kernel<<<dim3(128), dim3(256), 0, stream>>>(h1m, stats);
    bn_apply_kernel<<<dim3((N_NODES + 3) / 4), dim3(256), 0, stream>>>(
        h1m, stats, W2, pre2 + (size_t)m * N_NODES * NCLS);
  }

  spmm2_kernel<<<dim3((META * EDGES + 255) / 256), dim3(256), 0, stream>>>(
      sup_rows, sup_cols, sup_vals, pre2, h2);

  att_dot_kernel<<<dim3(64), dim3(256), 0, stream>>>(h2, w_omega, vacc);
  att_final_kernel<<<dim3(1), dim3(64), 0, stream>>>(vacc, b_omega, u_omega, alphas);

  sumsq_kernel<<<dim3(64), dim3(256), 0, stream>>>(W1, IN_DIM * NHID, scal + 3);
  sumsq_kernel<<<dim3(1), dim3(256), 0, stream>>>(W2, NHID * NCLS, scal + 3);
  sumsq_kernel<<<dim3(128), dim3(256), 0, stream>>>(w_omega, N_NODES * NCLS * META, scal + 3);
  sumsq_kernel<<<dim3(1), dim3(64), 0, stream>>>(b_omega, META, scal + 3);
  sumsq_kernel<<<dim3(1), dim3(64), 0, stream>>>(u_omega, META, scal + 3);

  loss_kernel<<<dim3((N_NODES + 255) / 256), dim3(256), 0, stream>>>(h2, alphas, label, mask, scal);
  final_kernel<<<dim3(1), dim3(64), 0, stream>>>(scal, out);
}

// Round 2
// 1224.347 us; speedup vs baseline: 5.0523x; 5.0523x over previous
//
#include <hip/hip_runtime.h>
#include <hip/hip_bf16.h>
#include <math.h>

#define N_NODES 50000
#define EDGES   800000
#define META    4
#define IN_DIM  512
#define NHID    128
#define NCLS    2
#define SCAN_NB 49   // ceil(50000/1024)

// ---------------- GEMM: pre1 = x @ W1  [50000,512]x[512,128] fp32 ----------------
__global__ __launch_bounds__(256) void gemm_xw1(const float* __restrict__ A,
                                                const float* __restrict__ B,
                                                float* __restrict__ C) {
  const int BM = 64, BK = 32;
  __shared__ float As[64][33];
  __shared__ float Bs[32][128];
  int tid = threadIdx.x;
  int block_row = blockIdx.x * BM;
  int tm = tid >> 5;        // 0..7 -> rows tm*8..tm*8+7
  int tn = tid & 31;        // 0..31 -> cols tn*4..tn*4+3
  float acc[8][4] = {};

  for (int k0 = 0; k0 < IN_DIM; k0 += BK) {
#pragma unroll
    for (int t = 0; t < 2; ++t) {
      int idx = t * 256 + tid;
      int row = idx >> 3, c4 = idx & 7;
      int grow = block_row + row;
      float4 v = make_float4(0.f, 0.f, 0.f, 0.f);
      if (grow < N_NODES)
        v = *reinterpret_cast<const float4*>(&A[(size_t)grow * IN_DIM + k0 + c4 * 4]);
      As[row][c4 * 4 + 0] = v.x; As[row][c4 * 4 + 1] = v.y;
      As[row][c4 * 4 + 2] = v.z; As[row][c4 * 4 + 3] = v.w;
    }
#pragma unroll
    for (int t = 0; t < 4; ++t) {
      int idx = t * 256 + tid;
      int row = idx >> 5, c4 = idx & 31;
      float4 v = *reinterpret_cast<const float4*>(&B[(size_t)(k0 + row) * NHID + c4 * 4]);
      *reinterpret_cast<float4*>(&Bs[row][c4 * 4]) = v;
    }
    __syncthreads();
#pragma unroll
    for (int kk = 0; kk < BK; ++kk) {
      float a[8];
#pragma unroll
      for (int r = 0; r < 8; ++r) a[r] = As[tm * 8 + r][kk];
      float4 bv = *reinterpret_cast<const float4*>(&Bs[kk][tn * 4]);
      float b[4] = {bv.x, bv.y, bv.z, bv.w};
#pragma unroll
      for (int r = 0; r < 8; ++r)
#pragma unroll
        for (int j = 0; j < 4; ++j)
          acc[r][j] = fmaf(a[r], b[j], acc[r][j]);
    }
    __syncthreads();
  }
#pragma unroll
  for (int r = 0; r < 8; ++r) {
    int grow = block_row + tm * 8 + r;
    if (grow < N_NODES)
      *reinterpret_cast<float4*>(&C[(size_t)grow * NHID + tn * 4]) =
          make_float4(acc[r][0], acc[r][1], acc[r][2], acc[r][3]);
  }
}

// ---------------- CSR build: histogram ----------------
__global__ __launch_bounds__(256) void hist_kernel(const int* __restrict__ rows,
                                                   int* __restrict__ counts) {
  int e = blockIdx.x * 256 + threadIdx.x;
  if (e < EDGES) atomicAdd(&counts[rows[e]], 1);
}

// ---------------- CSR build: scan stage 1 (per-1024-block exclusive partials) ----------------
__global__ __launch_bounds__(256) void scan1_kernel(const int* __restrict__ counts,
                                                    int* __restrict__ row_ptr,
                                                    int* __restrict__ blk) {
  __shared__ int lds[256];
  int b = blockIdx.x, t = threadIdx.x;
  int base = b * 1024 + t * 4;
  int v[4];
  int s = 0;
#pragma unroll
  for (int k = 0; k < 4; ++k) {
    int i = base + k;
    v[k] = (i < N_NODES) ? counts[i] : 0;
    s += v[k];
  }
  lds[t] = s;
  __syncthreads();
  for (int off = 1; off < 256; off <<= 1) {
    int add = (t >= off) ? lds[t - off] : 0;
    __syncthreads();
    lds[t] += add;
    __syncthreads();
  }
  int run = (t > 0) ? lds[t - 1] : 0;
  if (t == 255) blk[b] = lds[255];
#pragma unroll
  for (int k = 0; k < 4; ++k) {
    int i = base + k;
    if (i < N_NODES) row_ptr[i] = run;
    run += v[k];
  }
}

// ---------------- CSR build: scan stage 2 (block totals, serial, tiny) ----------------
__global__ void scan2_kernel(int* __restrict__ blk) {
  if (threadIdx.x == 0 && blockIdx.x == 0) {
    int run = 0;
    for (int i = 0; i < SCAN_NB; ++i) { int t = blk[i]; blk[i] = run; run += t; }
  }
}

// ---------------- CSR build: scan stage 3 (add block offsets; init cursor) ----------------
__global__ __launch_bounds__(256) void scan3_kernel(int* __restrict__ row_ptr,
                                                    int* __restrict__ cursor,
                                                    const int* __restrict__ blk) {
  int i = blockIdx.x * 256 + threadIdx.x;
  if (i < N_NODES) {
    int v = row_ptr[i] + blk[i >> 10];
    row_ptr[i] = v;
    cursor[i] = v;
  }
  if (i == 0) row_ptr[N_NODES] = EDGES;
}

// ---------------- CSR build: scatter edges into buckets ----------------
__global__ __launch_bounds__(256) void scatter_kernel(const int* __restrict__ rows,
                                                      const int* __restrict__ colsin,
                                                      const float* __restrict__ valsin,
                                                      int* __restrict__ cursor,
                                                      int* __restrict__ cols,
                                                      float* __restrict__ vals) {
  int e = blockIdx.x * 256 + threadIdx.x;
  if (e >= EDGES) return;
  int r = rows[e];
  int pos = atomicAdd(&cursor[r], 1);
  cols[pos] = colsin[e];
  vals[pos] = valsin[e];
}

// ---------------- SpMM layer 1 (gather): wave per row, 2 channels per lane ----------------
__global__ __launch_bounds__(256) void gather1_kernel(const int* __restrict__ row_ptr,
                                                      const int* __restrict__ cols,
                                                      const float* __restrict__ vals,
                                                      const float* __restrict__ dense,
                                                      float* __restrict__ h1) {
  int wv = threadIdx.x >> 6;
  int lane = threadIdx.x & 63;
  int r = blockIdx.x * 4 + wv;
  if (r >= N_NODES) return;
  int start = row_ptr[r], end = row_ptr[r + 1];
  float a0 = 0.f, a1 = 0.f;
  for (int j = start; j < end; ++j) {
    int c = cols[j];
    float v = vals[j];
    const float* d = &dense[(size_t)c * NHID];
    a0 = fmaf(v, d[lane], a0);
    a1 = fmaf(v, d[lane + 64], a1);
  }
  h1[(size_t)r * NHID + lane] = a0;
  h1[(size_t)r * NHID + lane + 64] = a1;
}

// ---------------- BN stats: per-channel sum and sumsq over nodes ----------------
__global__ __launch_bounds__(256) void bn_stats_kernel(const float* __restrict__ h1,
                                                       float* __restrict__ stats) {
  __shared__ float lds[256];
  int h = threadIdx.x & 127;
  int sub = threadIdx.x >> 7;
  float s = 0.f, ss = 0.f;
  int stride = gridDim.x * 2;
  for (int n = blockIdx.x * 2 + sub; n < N_NODES; n += stride) {
    float v = h1[(size_t)n * NHID + h];
    s += v;
    ss = fmaf(v, v, ss);
  }
  lds[threadIdx.x] = s;
  __syncthreads();
  if (sub == 0) s += lds[128 + h];
  __syncthreads();
  lds[threadIdx.x] = ss;
  __syncthreads();
  if (sub == 0) {
    ss += lds[128 + h];
    atomicAdd(&stats[h], s);
    atomicAdd(&stats[128 + h], ss);
  }
}

// ------------- BN apply + relu + @W2 -------------
__global__ __launch_bounds__(256) void bn_apply_kernel(const float* __restrict__ h1,
                                                       const float* __restrict__ stats,
                                                       const float* __restrict__ W2,
                                                       float* __restrict__ pre2) {
  int lane = threadIdx.x & 63;
  int wv = threadIdx.x >> 6;
  int n = blockIdx.x * 4 + wv;
  if (n >= N_NODES) return;
  const float inv_n = 1.0f / (float)N_NODES;
  float c0 = 0.f, c1 = 0.f;
#pragma unroll
  for (int t = 0; t < 2; ++t) {
    int h = lane + t * 64;
    float mean = stats[h] * inv_n;
    float var = stats[128 + h] * inv_n - mean * mean;
    float rs = rsqrtf(var + 1e-3f);
    float x = h1[(size_t)n * NHID + h];
    float y = (x - mean) * rs;
    y = y > 0.f ? y : 0.f;
    c0 = fmaf(y, W2[h * 2 + 0], c0);
    c1 = fmaf(y, W2[h * 2 + 1], c1);
  }
  for (int off = 32; off; off >>= 1) {
    c0 += __shfl_down(c0, off);
    c1 += __shfl_down(c1, off);
  }
  if (lane == 0) {
    pre2[(size_t)n * 2 + 0] = c0;
    pre2[(size_t)n * 2 + 1] = c1;
  }
}

// ---------------- SpMM layer 2 (gather): thread per row, 2 channels ----------------
__global__ __launch_bounds__(256) void gather2_kernel(const int* __restrict__ row_ptr,
                                                      const int* __restrict__ cols,
                                                      const float* __restrict__ vals,
                                                      const float* __restrict__ pre2m,
                                                      float* __restrict__ h2m) {
  int r = blockIdx.x * 256 + threadIdx.x;
  if (r >= N_NODES) return;
  int start = row_ptr[r], end = row_ptr[r + 1];
  float a0 = 0.f, a1 = 0.f;
  for (int j = start; j < end; ++j) {
    int c = cols[j];
    float v = vals[j];
    float2 d = *reinterpret_cast<const float2*>(&pre2m[(size_t)c * 2]);
    a0 = fmaf(v, d.x, a0);
    a1 = fmaf(v, d.y, a1);
  }
  h2m[(size_t)r * 2 + 0] = a0;
  h2m[(size_t)r * 2 + 1] = a1;
}

// ---------------- attention dot: vacc[m,j] = sum_i h2[m,i]*w_omega[i,j] ----------------
__global__ __launch_bounds__(256) void att_dot_kernel(const float* __restrict__ h2,
                                                      const float* __restrict__ w_omega,
                                                      float* __restrict__ vacc) {
  float acc[16] = {};
  int stride = gridDim.x * blockDim.x;
  for (int i = blockIdx.x * blockDim.x + threadIdx.x; i < N_NODES * NCLS; i += stride) {
    float4 w = *reinterpret_cast<const float4*>(&w_omega[(size_t)i * 4]);
#pragma unroll
    for (int m = 0; m < 4; ++m) {
      float f = h2[(size_t)m * (N_NODES * NCLS) + i];
      acc[m * 4 + 0] = fmaf(f, w.x, acc[m * 4 + 0]);
      acc[m * 4 + 1] = fmaf(f, w.y, acc[m * 4 + 1]);
      acc[m * 4 + 2] = fmaf(f, w.z, acc[m * 4 + 2]);
      acc[m * 4 + 3] = fmaf(f, w.w, acc[m * 4 + 3]);
    }
  }
#pragma unroll
  for (int q = 0; q < 16; ++q) {
    float v = acc[q];
    for (int off = 32; off; off >>= 1) v += __shfl_down(v, off);
    if ((threadIdx.x & 63) == 0) atomicAdd(&vacc[q], v);
  }
}

// ---------------- attention finalize ----------------
__global__ void att_final_kernel(const float* __restrict__ vacc,
                                 const float* __restrict__ b_omega,
                                 const float* __restrict__ u_omega,
                                 float* __restrict__ alphas) {
  if (threadIdx.x == 0 && blockIdx.x == 0) {
    float s[4];
    for (int m = 0; m < 4; ++m) {
      float sm = 0.f;
      for (int j = 0; j < 4; ++j)
        sm += tanhf(vacc[m * 4 + j] + b_omega[j]) * u_omega[j];
      s[m] = sm;
    }
    float mx = fmaxf(fmaxf(s[0], s[1]), fmaxf(s[2], s[3]));
    float ex[4], den = 0.f;
    for (int m = 0; m < 4; ++m) { ex[m] = expf(s[m] - mx); den += ex[m]; }
    for (int m = 0; m < 4; ++m) alphas[m] = ex[m] / den;
  }
}

// ---------------- sum of squares ----------------
__global__ __launch_bounds__(256) void sumsq_kernel(const float* __restrict__ p, int n,
                                                    float* __restrict__ out) {
  float s = 0.f;
  int stride = gridDim.x * blockDim.x;
  for (int i = blockIdx.x * blockDim.x + threadIdx.x; i < n; i += stride) {
    float v = p[i];
    s = fmaf(v, v, s);
  }
  for (int off = 32; off; off >>= 1) s += __shfl_down(s, off);
  if ((threadIdx.x & 63) == 0) atomicAdd(out, s);
}

// ---------------- per-node CE / acc / mask sums ----------------
__global__ __launch_bounds__(256) void loss_kernel(const float* __restrict__ h2,
                                                   const float* __restrict__ alphas,
                                                   const float* __restrict__ label,
                                                   const float* __restrict__ mask,
                                                   float* __restrict__ scal) {
  int n = blockIdx.x * blockDim.x + threadIdx.x;
  float msum = 0.f, cesum = 0.f, accsum = 0.f;
  if (n < N_NODES) {
    float a0 = alphas[0], a1 = alphas[1], a2 = alphas[2], a3 = alphas[3];
    const int S = N_NODES * NCLS;
    float l0 = a0 * h2[n * 2] + a1 * h2[S + n * 2] + a2 * h2[2 * S + n * 2] + a3 * h2[3 * S + n * 2];
    float l1 = a0 * h2[n * 2 + 1] + a1 * h2[S + n * 2 + 1] + a2 * h2[2 * S + n * 2 + 1] + a3 * h2[3 * S + n * 2 + 1];
    float mx = fmaxf(l0, l1);
    float lse = mx + logf(expf(l0 - mx) + expf(l1 - mx));
    float lb0 = label[n * 2], lb1 = label[n * 2 + 1];
    float ce = -(lb0 * (l0 - lse) + lb1 * (l1 - lse));
    int pred = (l1 > l0) ? 1 : 0;
    int larg = (lb1 > lb0) ? 1 : 0;
    float corr = (pred == larg) ? 1.f : 0.f;
    float mk = mask[n];
    msum = mk;
    cesum = ce * mk;
    accsum = corr * mk;
  }
  for (int off = 32; off; off >>= 1) {
    msum += __shfl_down(msum, off);
    cesum += __shfl_down(cesum, off);
    accsum += __shfl_down(accsum, off);
  }
  if ((threadIdx.x & 63) == 0) {
    atomicAdd(&scal[0], msum);
    atomicAdd(&scal[1], cesum);
    atomicAdd(&scal[2], accsum);
  }
}

__global__ void final_kernel(const float* __restrict__ scal, float* __restrict__ out) {
  if (threadIdx.x == 0 && blockIdx.x == 0) {
    out[0] = 5e-4f * 0.5f * scal[3] + scal[1] / scal[0];
    out[1] = scal[2] / scal[0];
  }
}

extern "C" void kernel_launch(void* const* d_in, const int* in_sizes, int n_in,
                              void* d_out, int out_size, void* d_ws, size_t ws_size,
                              hipStream_t stream) {
  const float* x       = (const float*)d_in[0];
  const float* W1      = (const float*)d_in[1];
  const float* W2      = (const float*)d_in[2];
  const float* w_omega = (const float*)d_in[3];
  const float* b_omega = (const float*)d_in[4];
  const float* u_omega = (const float*)d_in[5];
  const int*   sup_rows = (const int*)d_in[6];
  const int*   sup_cols = (const int*)d_in[7];
  const float* sup_vals = (const float*)d_in[8];
  const float* label   = (const float*)d_in[9];
  const float* mask    = (const float*)d_in[10];
  float* out = (float*)d_out;

  float* ws       = (float*)d_ws;
  float* pre1     = ws;                    // 6,400,000 f
  float* h1m      = ws + 6400000;          // 6,400,000 f (per-meta reuse)
  float* pre2     = ws + 12800000;         // 400,000 f [META][N][2]
  float* h2       = ws + 13200000;         // 400,000 f [META][N][2]
  float* csr_vals = ws + 13600000;         // 800,000 f (per-meta reuse)
  int*   csr_cols = (int*)(ws + 14400000); // 800,000 i
  int*   row_ptr  = (int*)(ws + 15200000); // 50,001 i
  int*   cursor   = (int*)(ws + 15250016); // 50,000 i
  int*   counts   = (int*)(ws + 15300032); // 50,000 i
  int*   blk      = (int*)(ws + 15350048); // 64 i
  float* stats    = ws + 15350144;         // 256 f
  float* vacc     = ws + 15350400;         // 16 f
  float* alphas   = ws + 15350416;         // 4 f
  float* scal     = ws + 15350420;         // 8 f [mask_sum, ce_sum, acc_sum, l2raw]

  // pre1 = x @ W1 (overlaps with first CSR build via stream order anyway)
  gemm_xw1<<<dim3((N_NODES + 63) / 64), dim3(256), 0, stream>>>(x, W1, pre1);

  hipMemsetAsync(scal, 0, 8 * sizeof(float), stream);
  hipMemsetAsync(vacc, 0, 16 * sizeof(float), stream);

  for (int m = 0; m < META; ++m) {
    const int*   mrows = sup_rows + (size_t)m * EDGES;
    const int*   mcols = sup_cols + (size_t)m * EDGES;
    const float* mvals = sup_vals + (size_t)m * EDGES;

    // ---- build per-meta CSR ----
    hipMemsetAsync(counts, 0, N_NODES * sizeof(int), stream);
    hist_kernel<<<dim3(3125), dim3(256), 0, stream>>>(mrows, counts);
    scan1_kernel<<<dim3(SCAN_NB), dim3(256), 0, stream>>>(counts, row_ptr, blk);
    scan2_kernel<<<dim3(1), dim3(64), 0, stream>>>(blk);
    scan3_kernel<<<dim3(196), dim3(256), 0, stream>>>(row_ptr, cursor, blk);
    scatter_kernel<<<dim3(3125), dim3(256), 0, stream>>>(mrows, mcols, mvals, cursor,
                                                         csr_cols, csr_vals);

    // ---- layer 1 gather + BN + layer-2 dense + layer-2 gather ----
    gather1_kernel<<<dim3((N_NODES + 3) / 4), dim3(256), 0, stream>>>(
        row_ptr, csr_cols, csr_vals, pre1, h1m);
    hipMemsetAsync(stats, 0, 256 * sizeof(float), stream);
    bn_stats_kernel<<<dim3(128), dim3(256), 0, stream>>>(h1m, stats);
    bn_apply_kernel<<<dim3((N_NODES + 3) / 4), dim3(256), 0, stream>>>(
        h1m, stats, W2, pre2 + (size_t)m * N_NODES * NCLS);
    gather2_kernel<<<dim3(196), dim3(256), 0, stream>>>(
        row_ptr, csr_cols, csr_vals, pre2 + (size_t)m * N_NODES * NCLS,
        h2 + (size_t)m * N_NODES * NCLS);
  }

  att_dot_kernel<<<dim3(64), dim3(256), 0, stream>>>(h2, w_omega, vacc);
  att_final_kernel<<<dim3(1), dim3(64), 0, stream>>>(vacc, b_omega, u_omega, alphas);

  sumsq_kernel<<<dim3(64), dim3(256), 0, stream>>>(W1, IN_DIM * NHID, scal + 3);
  sumsq_kernel<<<dim3(1), dim3(256), 0, stream>>>(W2, NHID * NCLS, scal + 3);
  sumsq_kernel<<<dim3(128), dim3(256), 0, stream>>>(w_omega, N_NODES * NCLS * META, scal + 3);
  sumsq_kernel<<<dim3(1), dim3(64), 0, stream>>>(b_omega, META, scal + 3);
  sumsq_kernel<<<dim3(1), dim3(64), 0, stream>>>(u_omega, META, scal + 3);

  loss_kernel<<<dim3((N_NODES + 255) / 256), dim3(256), 0, stream>>>(h2, alphas, label, mask, scal);
  final_kernel<<<dim3(1), dim3(64), 0, stream>>>(scal, out);
}

// Round 3
// 1076.787 us; speedup vs baseline: 5.7446x; 1.1370x over previous
//
#include <hip/hip_runtime.h>
#include <hip/hip_bf16.h>
#include <math.h>

#define N_NODES 50000
#define EDGES   800000
#define META    4
#define IN_DIM  512
#define NHID    128
#define NCLS    2
#define TOT_ROWS  (META * N_NODES)   // 200000
#define TOT_EDGES (META * EDGES)     // 3200000
#define SCAN_NB 196                  // ceil(200000/1024)

typedef __bf16 bf16x8 __attribute__((ext_vector_type(8)));
typedef float  f32x4  __attribute__((ext_vector_type(4)));

// ---------------- pack W1 into MFMA-fragment-ready bf16 hi/lo ----------------
// layout: frag index idx = (s*8 + t)*64 + l ; element i in 0..7
// holds W1[s*32 + (l>>4)*8 + i][t*16 + (l&15)]
__global__ __launch_bounds__(256) void pack_w1(const float* __restrict__ W1,
                                               __bf16* __restrict__ Wh,
                                               __bf16* __restrict__ Wl) {
  int idx = blockIdx.x * 256 + threadIdx.x;
  if (idx >= 16 * 8 * 64) return;
  int l = idx & 63, st = idx >> 6, t = st & 7, s = st >> 3;
  int col = t * 16 + (l & 15);
  int k0 = s * 32 + (l >> 4) * 8;
#pragma unroll
  for (int i = 0; i < 8; ++i) {
    float w = W1[(size_t)(k0 + i) * NHID + col];
    __bf16 h = (__bf16)w;
    Wh[(size_t)idx * 8 + i] = h;
    Wl[(size_t)idx * 8 + i] = (__bf16)(w - (float)h);
  }
}

// ---------------- GEMM: pre1 = x @ W1 via bf16x3 MFMA ----------------
__global__ __launch_bounds__(256) void gemm_mfma(const float* __restrict__ X,
                                                 const __bf16* __restrict__ Wh,
                                                 const __bf16* __restrict__ Wl,
                                                 float* __restrict__ C) {
  int w = threadIdx.x >> 6, l = threadIdx.x & 63;
  int lrow = l & 15, lk = l >> 4;
  int row = blockIdx.x * 64 + w * 16 + lrow;
  int rowc = row < N_NODES ? row : N_NODES - 1;
  f32x4 acc[8] = {};
  const bf16x8* whv = (const bf16x8*)Wh;
  const bf16x8* wlv = (const bf16x8*)Wl;

  for (int s = 0; s < 16; ++s) {
    const float* ap = &X[(size_t)rowc * IN_DIM + s * 32 + lk * 8];
    float4 a0 = *reinterpret_cast<const float4*>(ap);
    float4 a1 = *reinterpret_cast<const float4*>(ap + 4);
    float av[8] = {a0.x, a0.y, a0.z, a0.w, a1.x, a1.y, a1.z, a1.w};
    bf16x8 ah, al;
#pragma unroll
    for (int i = 0; i < 8; ++i) {
      float v = av[i];
      __bf16 h = (__bf16)v;
      ah[i] = h;
      al[i] = (__bf16)(v - (float)h);
    }
    int fbase = (s * 8) * 64 + l;
#pragma unroll
    for (int t = 0; t < 8; ++t) {
      bf16x8 bh = whv[fbase + t * 64];
      bf16x8 bl = wlv[fbase + t * 64];
      acc[t] = __builtin_amdgcn_mfma_f32_16x16x32_bf16(ah, bh, acc[t], 0, 0, 0);
      acc[t] = __builtin_amdgcn_mfma_f32_16x16x32_bf16(ah, bl, acc[t], 0, 0, 0);
      acc[t] = __builtin_amdgcn_mfma_f32_16x16x32_bf16(al, bh, acc[t], 0, 0, 0);
    }
  }
  // C layout: col = lane&15 (+t*16), row = (lane>>4)*4 + reg  [m89-verified]
  int crow0 = blockIdx.x * 64 + w * 16 + lk * 4;
#pragma unroll
  for (int t = 0; t < 8; ++t) {
    int col = t * 16 + lrow;
#pragma unroll
    for (int r = 0; r < 4; ++r) {
      int crow = crow0 + r;
      if (crow < N_NODES) C[(size_t)crow * NHID + col] = acc[t][r];
    }
  }
}

// ---------------- CSR build (all 4 metas at once) ----------------
__global__ __launch_bounds__(256) void hist_all(const int* __restrict__ rows,
                                                int* __restrict__ counts) {
  int e = blockIdx.x * 256 + threadIdx.x;
  if (e < TOT_EDGES) {
    int m = e / EDGES;
    atomicAdd(&counts[m * N_NODES + rows[e]], 1);
  }
}

__global__ __launch_bounds__(256) void scan1_kernel(const int* __restrict__ counts,
                                                    int* __restrict__ row_ptr,
                                                    int* __restrict__ blk) {
  __shared__ int lds[256];
  int b = blockIdx.x, t = threadIdx.x;
  int base = b * 1024 + t * 4;
  int v[4];
  int s = 0;
#pragma unroll
  for (int k = 0; k < 4; ++k) {
    int i = base + k;
    v[k] = (i < TOT_ROWS) ? counts[i] : 0;
    s += v[k];
  }
  lds[t] = s;
  __syncthreads();
  for (int off = 1; off < 256; off <<= 1) {
    int add = (t >= off) ? lds[t - off] : 0;
    __syncthreads();
    lds[t] += add;
    __syncthreads();
  }
  int run = (t > 0) ? lds[t - 1] : 0;
  if (t == 255) blk[b] = lds[255];
#pragma unroll
  for (int k = 0; k < 4; ++k) {
    int i = base + k;
    if (i < TOT_ROWS) row_ptr[i] = run;
    run += v[k];
  }
}

__global__ void scan2_kernel(int* __restrict__ blk) {
  if (threadIdx.x == 0 && blockIdx.x == 0) {
    int run = 0;
    for (int i = 0; i < SCAN_NB; ++i) { int t = blk[i]; blk[i] = run; run += t; }
  }
}

__global__ __launch_bounds__(256) void scan3_kernel(int* __restrict__ row_ptr,
                                                    int* __restrict__ cursor,
                                                    const int* __restrict__ blk) {
  int i = blockIdx.x * 256 + threadIdx.x;
  if (i < TOT_ROWS) {
    int v = row_ptr[i] + blk[i >> 10];
    row_ptr[i] = v;
    cursor[i] = v;
  }
  if (i == 0) row_ptr[TOT_ROWS] = TOT_EDGES;
}

__global__ __launch_bounds__(256) void scatter_all(const int* __restrict__ rows,
                                                   const int* __restrict__ colsin,
                                                   const float* __restrict__ valsin,
                                                   int* __restrict__ cursor,
                                                   int* __restrict__ cols,
                                                   float* __restrict__ vals) {
  int e = blockIdx.x * 256 + threadIdx.x;
  if (e >= TOT_EDGES) return;
  int m = e / EDGES;
  int pos = atomicAdd(&cursor[m * N_NODES + rows[e]], 1);
  cols[pos] = colsin[e];
  vals[pos] = valsin[e];
}

// ---------------- SpMM layer 1 (gather): wave per row ----------------
__global__ __launch_bounds__(256) void gather1_kernel(const int* __restrict__ row_ptr,
                                                      const int* __restrict__ cols,
                                                      const float* __restrict__ vals,
                                                      const float* __restrict__ dense,
                                                      float* __restrict__ h1) {
  int wv = threadIdx.x >> 6;
  int lane = threadIdx.x & 63;
  int r = blockIdx.x * 4 + wv;
  if (r >= N_NODES) return;
  int start = row_ptr[r], end = row_ptr[r + 1];
  float a0 = 0.f, a1 = 0.f;
  for (int j = start; j < end; ++j) {
    int c = cols[j];
    float v = vals[j];
    const float* d = &dense[(size_t)c * NHID];
    a0 = fmaf(v, d[lane], a0);
    a1 = fmaf(v, d[lane + 64], a1);
  }
  h1[(size_t)r * NHID + lane] = a0;
  h1[(size_t)r * NHID + lane + 64] = a1;
}

// ---------------- BN stats: float4, block partials, few atomics ----------------
__global__ __launch_bounds__(256) void bn_stats_kernel(const float* __restrict__ h1,
                                                       float* __restrict__ stats) {
  __shared__ float ls[8][32][4];
  __shared__ float lq[8][32][4];
  int c4 = threadIdx.x & 31;
  int rg = threadIdx.x >> 5;
  float s0 = 0, s1 = 0, s2 = 0, s3 = 0, q0 = 0, q1 = 0, q2 = 0, q3 = 0;
  for (int n = blockIdx.x * 8 + rg; n < N_NODES; n += gridDim.x * 8) {
    float4 v = *reinterpret_cast<const float4*>(&h1[(size_t)n * NHID + c4 * 4]);
    s0 += v.x; s1 += v.y; s2 += v.z; s3 += v.w;
    q0 = fmaf(v.x, v.x, q0); q1 = fmaf(v.y, v.y, q1);
    q2 = fmaf(v.z, v.z, q2); q3 = fmaf(v.w, v.w, q3);
  }
  ls[rg][c4][0] = s0; ls[rg][c4][1] = s1; ls[rg][c4][2] = s2; ls[rg][c4][3] = s3;
  lq[rg][c4][0] = q0; lq[rg][c4][1] = q1; lq[rg][c4][2] = q2; lq[rg][c4][3] = q3;
  __syncthreads();
  if (rg == 0) {
#pragma unroll
    for (int w = 1; w < 8; ++w) {
      s0 += ls[w][c4][0]; s1 += ls[w][c4][1]; s2 += ls[w][c4][2]; s3 += ls[w][c4][3];
      q0 += lq[w][c4][0]; q1 += lq[w][c4][1]; q2 += lq[w][c4][2]; q3 += lq[w][c4][3];
    }
    atomicAdd(&stats[c4 * 4 + 0], s0); atomicAdd(&stats[c4 * 4 + 1], s1);
    atomicAdd(&stats[c4 * 4 + 2], s2); atomicAdd(&stats[c4 * 4 + 3], s3);
    atomicAdd(&stats[128 + c4 * 4 + 0], q0); atomicAdd(&stats[128 + c4 * 4 + 1], q1);
    atomicAdd(&stats[128 + c4 * 4 + 2], q2); atomicAdd(&stats[128 + c4 * 4 + 3], q3);
  }
}

// ------------- BN apply + relu + @W2 -------------
__global__ __launch_bounds__(256) void bn_apply_kernel(const float* __restrict__ h1,
                                                       const float* __restrict__ stats,
                                                       const float* __restrict__ W2,
                                                       float* __restrict__ pre2) {
  int lane = threadIdx.x & 63;
  int wv = threadIdx.x >> 6;
  int n = blockIdx.x * 4 + wv;
  if (n >= N_NODES) return;
  const float inv_n = 1.0f / (float)N_NODES;
  float c0 = 0.f, c1 = 0.f;
#pragma unroll
  for (int t = 0; t < 2; ++t) {
    int h = lane + t * 64;
    float mean = stats[h] * inv_n;
    float var = stats[128 + h] * inv_n - mean * mean;
    float rs = rsqrtf(var + 1e-3f);
    float x = h1[(size_t)n * NHID + h];
    float y = (x - mean) * rs;
    y = y > 0.f ? y : 0.f;
    c0 = fmaf(y, W2[h * 2 + 0], c0);
    c1 = fmaf(y, W2[h * 2 + 1], c1);
  }
  for (int off = 32; off; off >>= 1) {
    c0 += __shfl_down(c0, off);
    c1 += __shfl_down(c1, off);
  }
  if (lane == 0) {
    pre2[(size_t)n * 2 + 0] = c0;
    pre2[(size_t)n * 2 + 1] = c1;
  }
}

// ---------------- SpMM layer 2 (gather), all metas ----------------
__global__ __launch_bounds__(256) void gather2_all(const int* __restrict__ row_ptr,
                                                   const int* __restrict__ cols,
                                                   const float* __restrict__ vals,
                                                   const float* __restrict__ pre2,
                                                   float* __restrict__ h2) {
  int r = blockIdx.x * 256 + threadIdx.x;
  int m = blockIdx.y;
  if (r >= N_NODES) return;
  int start = row_ptr[m * N_NODES + r], end = row_ptr[m * N_NODES + r + 1];
  const float* p = pre2 + (size_t)m * N_NODES * 2;
  float a0 = 0.f, a1 = 0.f;
  for (int j = start; j < end; ++j) {
    int c = cols[j];
    float v = vals[j];
    a0 = fmaf(v, p[c * 2 + 0], a0);
    a1 = fmaf(v, p[c * 2 + 1], a1);
  }
  h2[((size_t)m * N_NODES + r) * 2 + 0] = a0;
  h2[((size_t)m * N_NODES + r) * 2 + 1] = a1;
}

// ---------------- attention dot ----------------
__global__ __launch_bounds__(256) void att_dot_kernel(const float* __restrict__ h2,
                                                      const float* __restrict__ w_omega,
                                                      float* __restrict__ vacc) {
  float acc[16] = {};
  int stride = gridDim.x * blockDim.x;
  for (int i = blockIdx.x * blockDim.x + threadIdx.x; i < N_NODES * NCLS; i += stride) {
    float4 w = *reinterpret_cast<const float4*>(&w_omega[(size_t)i * 4]);
#pragma unroll
    for (int m = 0; m < 4; ++m) {
      float f = h2[(size_t)m * (N_NODES * NCLS) + i];
      acc[m * 4 + 0] = fmaf(f, w.x, acc[m * 4 + 0]);
      acc[m * 4 + 1] = fmaf(f, w.y, acc[m * 4 + 1]);
      acc[m * 4 + 2] = fmaf(f, w.z, acc[m * 4 + 2]);
      acc[m * 4 + 3] = fmaf(f, w.w, acc[m * 4 + 3]);
    }
  }
#pragma unroll
  for (int q = 0; q < 16; ++q) {
    float v = acc[q];
    for (int off = 32; off; off >>= 1) v += __shfl_down(v, off);
    if ((threadIdx.x & 63) == 0) atomicAdd(&vacc[q], v);
  }
}

// ---------------- attention finalize ----------------
__global__ void att_final_kernel(const float* __restrict__ vacc,
                                 const float* __restrict__ b_omega,
                                 const float* __restrict__ u_omega,
                                 float* __restrict__ alphas) {
  if (threadIdx.x == 0 && blockIdx.x == 0) {
    float s[4];
    for (int m = 0; m < 4; ++m) {
      float sm = 0.f;
      for (int j = 0; j < 4; ++j)
        sm += tanhf(vacc[m * 4 + j] + b_omega[j]) * u_omega[j];
      s[m] = sm;
    }
    float mx = fmaxf(fmaxf(s[0], s[1]), fmaxf(s[2], s[3]));
    float ex[4], den = 0.f;
    for (int m = 0; m < 4; ++m) { ex[m] = expf(s[m] - mx); den += ex[m]; }
    for (int m = 0; m < 4; ++m) alphas[m] = ex[m] / den;
  }
}

// ---------------- fused sum of squares over all 5 params ----------------
#define SQ0 400000            // w_omega
#define SQ1 (SQ0 + 65536)     // + W1
#define SQ2 (SQ1 + 256)       // + W2
#define SQ3 (SQ2 + 4)         // + b_omega
#define SQ4 (SQ3 + 4)         // + u_omega
__global__ __launch_bounds__(256) void sumsq_all(const float* __restrict__ w_omega,
                                                 const float* __restrict__ W1,
                                                 const float* __restrict__ W2,
                                                 const float* __restrict__ b_omega,
                                                 const float* __restrict__ u_omega,
                                                 float* __restrict__ out) {
  float s = 0.f;
  int stride = gridDim.x * blockDim.x;
  for (int i = blockIdx.x * blockDim.x + threadIdx.x; i < SQ4; i += stride) {
    float v;
    if (i < SQ0) v = w_omega[i];
    else if (i < SQ1) v = W1[i - SQ0];
    else if (i < SQ2) v = W2[i - SQ1];
    else if (i < SQ3) v = b_omega[i - SQ2];
    else v = u_omega[i - SQ3];
    s = fmaf(v, v, s);
  }
  for (int off = 32; off; off >>= 1) s += __shfl_down(s, off);
  if ((threadIdx.x & 63) == 0) atomicAdd(out, s);
}

// ---------------- per-node CE / acc / mask sums ----------------
__global__ __launch_bounds__(256) void loss_kernel(const float* __restrict__ h2,
                                                   const float* __restrict__ alphas,
                                                   const float* __restrict__ label,
                                                   const float* __restrict__ mask,
                                                   float* __restrict__ scal) {
  int n = blockIdx.x * blockDim.x + threadIdx.x;
  float msum = 0.f, cesum = 0.f, accsum = 0.f;
  if (n < N_NODES) {
    float a0 = alphas[0], a1 = alphas[1], a2 = alphas[2], a3 = alphas[3];
    const int S = N_NODES * NCLS;
    float l0 = a0 * h2[n * 2] + a1 * h2[S + n * 2] + a2 * h2[2 * S + n * 2] + a3 * h2[3 * S + n * 2];
    float l1 = a0 * h2[n * 2 + 1] + a1 * h2[S + n * 2 + 1] + a2 * h2[2 * S + n * 2 + 1] + a3 * h2[3 * S + n * 2 + 1];
    float mx = fmaxf(l0, l1);
    float lse = mx + logf(expf(l0 - mx) + expf(l1 - mx));
    float lb0 = label[n * 2], lb1 = label[n * 2 + 1];
    float ce = -(lb0 * (l0 - lse) + lb1 * (l1 - lse));
    int pred = (l1 > l0) ? 1 : 0;
    int larg = (lb1 > lb0) ? 1 : 0;
    float corr = (pred == larg) ? 1.f : 0.f;
    float mk = mask[n];
    msum = mk;
    cesum = ce * mk;
    accsum = corr * mk;
  }
  for (int off = 32; off; off >>= 1) {
    msum += __shfl_down(msum, off);
    cesum += __shfl_down(cesum, off);
    accsum += __shfl_down(accsum, off);
  }
  if ((threadIdx.x & 63) == 0) {
    atomicAdd(&scal[0], msum);
    atomicAdd(&scal[1], cesum);
    atomicAdd(&scal[2], accsum);
  }
}

__global__ void final_kernel(const float* __restrict__ scal, float* __restrict__ out) {
  if (threadIdx.x == 0 && blockIdx.x == 0) {
    out[0] = 5e-4f * 0.5f * scal[3] + scal[1] / scal[0];
    out[1] = scal[2] / scal[0];
  }
}

extern "C" void kernel_launch(void* const* d_in, const int* in_sizes, int n_in,
                              void* d_out, int out_size, void* d_ws, size_t ws_size,
                              hipStream_t stream) {
  const float* x       = (const float*)d_in[0];
  const float* W1      = (const float*)d_in[1];
  const float* W2      = (const float*)d_in[2];
  const float* w_omega = (const float*)d_in[3];
  const float* b_omega = (const float*)d_in[4];
  const float* u_omega = (const float*)d_in[5];
  const int*   sup_rows = (const int*)d_in[6];
  const int*   sup_cols = (const int*)d_in[7];
  const float* sup_vals = (const float*)d_in[8];
  const float* label   = (const float*)d_in[9];
  const float* mask    = (const float*)d_in[10];
  float* out = (float*)d_out;

  float* ws = (float*)d_ws;
  float* pre1     = ws;                        // 6,400,000 f
  float* h1m      = ws + 6400000;              // 6,400,000 f (per-meta reuse)
  float* pre2     = ws + 12800000;             // 400,000 f [META][N][2]
  float* h2       = ws + 13200000;             // 400,000 f [META][N][2]
  float* csr_vals = ws + 13600000;             // 3,200,000 f
  int*   csr_cols = (int*)(ws + 16800000);     // 3,200,000 i
  int*   row_ptr  = (int*)(ws + 20000000);     // 200,001 i
  int*   cursor   = (int*)(ws + 20200064);     // 200,000 i
  int*   counts   = (int*)(ws + 20400064);     // 200,000 i
  int*   blk      = (int*)(ws + 20600064);     // 256 i
  float* stats    = ws + 20600320;             // 1,024 f  [META][256]
  float* scal     = ws + 20601344;             // 8 f [mask_sum, ce_sum, acc_sum, l2raw]
  float* vacc     = ws + 20601352;             // 16 f
  float* alphas   = ws + 20601368;             // 4 f
  __bf16* Wh      = (__bf16*)(ws + 20601376);  // 65,536 bf16
  __bf16* Wl      = (__bf16*)(ws + 20634144);  // 65,536 bf16

  // ---- GEMM path: pack W1 then bf16x3 MFMA ----
  pack_w1<<<dim3(32), dim3(256), 0, stream>>>(W1, Wh, Wl);
  gemm_mfma<<<dim3(782), dim3(256), 0, stream>>>(x, Wh, Wl, pre1);

  // ---- zero accumulators (stats..vacc contiguous: 1024+8+16 floats) ----
  hipMemsetAsync(counts, 0, TOT_ROWS * sizeof(int), stream);
  hipMemsetAsync(stats, 0, (1024 + 8 + 16) * sizeof(float), stream);

  // ---- CSR build, all 4 metas in one pass ----
  hist_all<<<dim3(12500), dim3(256), 0, stream>>>(sup_rows, counts);
  scan1_kernel<<<dim3(SCAN_NB), dim3(256), 0, stream>>>(counts, row_ptr, blk);
  scan2_kernel<<<dim3(1), dim3(64), 0, stream>>>(blk);
  scan3_kernel<<<dim3(782), dim3(256), 0, stream>>>(row_ptr, cursor, blk);
  scatter_all<<<dim3(12500), dim3(256), 0, stream>>>(sup_rows, sup_cols, sup_vals,
                                                     cursor, csr_cols, csr_vals);

  // ---- per-meta: gather1 -> stats -> bn+W2 ----
  for (int m = 0; m < META; ++m) {
    gather1_kernel<<<dim3(12500), dim3(256), 0, stream>>>(
        row_ptr + (size_t)m * N_NODES, csr_cols, csr_vals, pre1, h1m);
    bn_stats_kernel<<<dim3(192), dim3(256), 0, stream>>>(h1m, stats + m * 256);
    bn_apply_kernel<<<dim3(12500), dim3(256), 0, stream>>>(
        h1m, stats + m * 256, W2, pre2 + (size_t)m * N_NODES * NCLS);
  }

  gather2_all<<<dim3(196, 4), dim3(256), 0, stream>>>(row_ptr, csr_cols, csr_vals, pre2, h2);

  att_dot_kernel<<<dim3(64), dim3(256), 0, stream>>>(h2, w_omega, vacc);
  att_final_kernel<<<dim3(1), dim3(64), 0, stream>>>(vacc, b_omega, u_omega, alphas);

  sumsq_all<<<dim3(128), dim3(256), 0, stream>>>(w_omega, W1, W2, b_omega, u_omega, scal + 3);

  loss_kernel<<<dim3(196), dim3(256), 0, stream>>>(h2, alphas, label, mask, scal);
  final_kernel<<<dim3(1), dim3(64), 0, stream>>>(scal, out);
}